// Round 11
// baseline (686.374 us; speedup 1.0000x reference)
//
#include <hip/hip_runtime.h>

// Side Window Filter — bit-exact vs harness np ref (absmax 0.0 contract).
// Math contract (DO NOT REORDER): per output, each of the 8 windows is a
// sequential __builtin_fmaf chain over its taps in row-major (i,j) order,
// fp32 accumulator starting at 0, weights fp32(1/15), fp32(1/9); replicate
// boundary; 8 iterations; fp32 iterates; fp32 d/argmin(first-idx)/update;
// final clip(|x0-res|,0,255).
//
// R21: single-row structure + explicit software-pipelined row prefetch.
// Why: R19/R20 post-mortems show the pair structure's persistent set
// (64 acc + 8 center = 72 floats) against the allocator's empirically
// pinned ~84-reg allocation leaves ~12 regs for the 20-float window, so
// loads are forced next to uses and every L2 miss (~200-600 cyc) lands
// on the critical path -> all variants plateau at 57-70 us/dispatch with
// VALU ~50% and memory ~30% (latency-bound, nothing saturated).
// Single row: persistent = 32 acc + 4 center = 36 floats -> room for TWO
// full 20-float windows (q=current row, p=next row). The p-loads are
// issued BEFORE row j's 128-fma block (~256 cyc ~= L2 latency), hiding
// the chain. Accepted trade: 6.25 float4 loads/output (vs pair's 3.75)
// -> L1-port ceiling ~32 us/dispatch, still well under the 57 us status
// quo. Keeps: XCD y-banding (R17/R19: FETCH 103->56 MB) and the
// waves_per_eu(3,3)+launch_bounds(256) combo (only allocator-sane one).
// fma chain order byte-identical to R10/R19 (bit-exact).

static constexpr int H    = 2048;
static constexpr int W    = 2048;
static constexpr int C    = 3;
static constexpr int WC   = W * C;     // 6144 floats per row
static constexpr int NBX  = 6;         // x-blocks (256 thr x 4 cols)
static constexpr int BAND = H / 8;     // 256 rows per XCD band

// One window-row phase of the 8 directional chains for one output column.
// ph is compile-time at every call site (unrolled loops) so branches fold.
// Chain statement order is IDENTICAL to the verified R10/R15/R19 kernels.
__device__ __forceinline__ void apply_phase_t(float* __restrict__ a,
                                              float t0, float t1, float t2,
                                              float t3, float t4,
                                              int ph, float& center,
                                              float w15, float w9) {
  if (ph == 2) center = t2;
  // L: cols 0..2, all rows
  a[0]=__builtin_fmaf(w15,t0,a[0]); a[0]=__builtin_fmaf(w15,t1,a[0]); a[0]=__builtin_fmaf(w15,t2,a[0]);
  // R: cols 2..4, all rows
  a[1]=__builtin_fmaf(w15,t2,a[1]); a[1]=__builtin_fmaf(w15,t3,a[1]); a[1]=__builtin_fmaf(w15,t4,a[1]);
  if (ph <= 2) {  // U: rows 0..2, all cols
    a[2]=__builtin_fmaf(w15,t0,a[2]); a[2]=__builtin_fmaf(w15,t1,a[2]); a[2]=__builtin_fmaf(w15,t2,a[2]);
    a[2]=__builtin_fmaf(w15,t3,a[2]); a[2]=__builtin_fmaf(w15,t4,a[2]);
    // NW / NE
    a[4]=__builtin_fmaf(w9,t0,a[4]); a[4]=__builtin_fmaf(w9,t1,a[4]); a[4]=__builtin_fmaf(w9,t2,a[4]);
    a[5]=__builtin_fmaf(w9,t2,a[5]); a[5]=__builtin_fmaf(w9,t3,a[5]); a[5]=__builtin_fmaf(w9,t4,a[5]);
  }
  if (ph >= 2) {  // D: rows 2..4, all cols
    a[3]=__builtin_fmaf(w15,t0,a[3]); a[3]=__builtin_fmaf(w15,t1,a[3]); a[3]=__builtin_fmaf(w15,t2,a[3]);
    a[3]=__builtin_fmaf(w15,t3,a[3]); a[3]=__builtin_fmaf(w15,t4,a[3]);
    // SW / SE
    a[6]=__builtin_fmaf(w9,t0,a[6]); a[6]=__builtin_fmaf(w9,t1,a[6]); a[6]=__builtin_fmaf(w9,t2,a[6]);
    a[7]=__builtin_fmaf(w9,t2,a[7]); a[7]=__builtin_fmaf(w9,t3,a[7]); a[7]=__builtin_fmaf(w9,t4,a[7]);
  }
}

// fp32 d/argmin/update epilogue for one output column (order-contractual).
__device__ __forceinline__ float finish(const float* __restrict__ a,
                                        float center) {
  float best  = a[0] - center;
  float besta = fabsf(best);
#pragma unroll
  for (int m = 1; m < 8; ++m) {
    const float d  = a[m] - center;
    const float ab = fabsf(d);
    if (ab < besta) { besta = ab; best = d; }
  }
  return center + best;
}

template<bool FINAL>
__global__ __attribute__((amdgpu_waves_per_eu(3, 3))) __launch_bounds__(256)
void swf_sr(const float* __restrict__ src, float* __restrict__ dst,
            const float* __restrict__ x0) {
  // XCD-contiguous y-banding (R17/R19-proven): flat%8 ~ XCD id selects a
  // contiguous 256-row band. 12288 blocks, 12288%8==0 -> bijective.
  const int flat = blockIdx.y * NBX + blockIdx.x;
  const int xcd  = flat & 7;
  const int idx  = flat >> 3;
  const int yb   = idx / NBX;
  const int xb   = idx - yb * NBX;
  const int y    = xcd * BAND + yb;                 // output row
  const int col4 = (xb * 256 + threadIdx.x) * 4;    // 16B-aligned

  const float w15 = 1.0f / 15.0f;   // fp32(1/15)
  const float w9  = 1.0f / 9.0f;    // fp32(1/9)

  float acc[4][8];
#pragma unroll
  for (int k = 0; k < 4; ++k)
#pragma unroll
    for (int m = 0; m < 8; ++m) acc[k][m] = 0.0f;
  float center[4];

  // fast iff all taps for cols col4..col4+3 lie in [col4-8, col4+12)
  const bool fastc = (col4 >= 8) && (col4 <= WC - 12);
  if (fastc) {
    const float* colbase = src + (col4 - 8);

    // prime: window row j=0 (abs row y-2, top clamp)
    int hy0 = y - 2;
    hy0 = hy0 < 0 ? 0 : hy0;
    const float4* rp0 = (const float4*)(colbase + (size_t)hy0 * WC);
    float4 q0 = rp0[0], q1 = rp0[1], q2 = rp0[2], q3 = rp0[3], q4 = rp0[4];

    // pipelined walk: issue row j+1 loads BEFORE row j's fma block
#pragma unroll
    for (int j = 0; j < 5; ++j) {
      float4 p0, p1, p2, p3, p4;
      if (j < 4) {
        int hy = y + (j + 1) - 2;
        hy = hy < 0 ? 0 : (hy > H - 1 ? H - 1 : hy);   // replicate rows
        const float4* rp = (const float4*)(colbase + (size_t)hy * WC);
        p0 = rp[0]; p1 = rp[1]; p2 = rp[2]; p3 = rp[3]; p4 = rp[4];
      }
      const float r[20] = {q0.x,q0.y,q0.z,q0.w, q1.x,q1.y,q1.z,q1.w,
                           q2.x,q2.y,q2.z,q2.w, q3.x,q3.y,q3.z,q3.w,
                           q4.x,q4.y,q4.z,q4.w};
#pragma unroll
      for (int k = 0; k < 4; ++k) {
        // tap jx of output col4+k -> r[k + 3*jx + 2]
        const float t0 = r[k+2], t1 = r[k+5], t2 = r[k+8],
                    t3 = r[k+11], t4 = r[k+14];
        apply_phase_t(acc[k], t0,t1,t2,t3,t4, j, center[k], w15, w9);
      }
      if (j < 4) { q0 = p0; q1 = p1; q2 = p2; q3 = p3; q4 = p4; }
    }
  } else {
    // edge columns (col4 in {0,4,WC-8,WC-4}): build the same 20-float
    // window per row via pixel-clamped scalar loads (halo identity,
    // verified absmax 0.0 in R16/R18/R20: float x <-> unclamped idx
    // f = col4-8+x; f<0 -> ((f%3)+3)%3, f>=WC -> (W-1)*3+f%3).
    const int base = col4 - 8;
#pragma unroll
    for (int j = 0; j < 5; ++j) {
      int hy = y + j - 2;
      hy = hy < 0 ? 0 : (hy > H - 1 ? H - 1 : hy);
      const float* rr = src + (size_t)hy * WC;
      float r[20];
#pragma unroll
      for (int x = 0; x < 20; ++x) {
        const int f  = base + x;
        const int ix = (f < 0)    ? ((f % 3) + 3) % 3
                     : (f >= WC)  ? (W - 1) * 3 + (f % 3)
                     : f;
        r[x] = rr[ix];
      }
#pragma unroll
      for (int k = 0; k < 4; ++k) {
        const float t0 = r[k+2], t1 = r[k+5], t2 = r[k+8],
                    t3 = r[k+11], t4 = r[k+14];
        apply_phase_t(acc[k], t0,t1,t2,t3,t4, j, center[k], w15, w9);
      }
    }
  }

  // epilogue: fp32 d/argmin/update (+ optional diff/clip), float4 store
  float4 xv4;
  if (FINAL) xv4 = *(const float4*)(x0 + (size_t)y * WC + col4);
  float o[4];
#pragma unroll
  for (int k = 0; k < 4; ++k) {
    const float res = finish(acc[k], center[k]);
    if (FINAL) {
      const float xv = (k == 0) ? xv4.x : (k == 1) ? xv4.y
                     : (k == 2) ? xv4.z : xv4.w;
      float diff = fabsf(xv - res);
      o[k] = diff > 255.0f ? 255.0f : diff;
    } else {
      o[k] = res;
    }
  }
  float4 ov;
  ov.x = o[0]; ov.y = o[1]; ov.z = o[2]; ov.w = o[3];
  *(float4*)(dst + (size_t)y * WC + col4) = ov;
}

extern "C" void kernel_launch(void* const* d_in, const int* in_sizes, int n_in,
                              void* d_out, int out_size, void* d_ws, size_t ws_size,
                              hipStream_t stream) {
  const float* x0  = (const float*)d_in[0];
  float*       out = (float*)d_out;
  float*       ws  = (float*)d_ws;   // needs H*W*C*4 = 50.3 MB

  dim3 grid(NBX, H);                 // 6 x-blocks, 2048 rows
  dim3 block(256);

  swf_sr<false><<<grid, block, 0, stream>>>(x0,  ws,  nullptr);  // iter 1
  swf_sr<false><<<grid, block, 0, stream>>>(ws,  out, nullptr);  // iter 2
  swf_sr<false><<<grid, block, 0, stream>>>(out, ws,  nullptr);  // iter 3
  swf_sr<false><<<grid, block, 0, stream>>>(ws,  out, nullptr);  // iter 4
  swf_sr<false><<<grid, block, 0, stream>>>(out, ws,  nullptr);  // iter 5
  swf_sr<false><<<grid, block, 0, stream>>>(ws,  out, nullptr);  // iter 6
  swf_sr<false><<<grid, block, 0, stream>>>(out, ws,  nullptr);  // iter 7
  swf_sr<true ><<<grid, block, 0, stream>>>(ws,  out, x0);       // iter 8 + diff
}

// Round 12
// 523.721 us; speedup vs baseline: 1.3106x; 1.3106x over previous
//
#include <hip/hip_runtime.h>

// Side Window Filter — bit-exact vs harness np ref (absmax 0.0 contract).
// Math contract (DO NOT REORDER): per output, each of the 8 windows is a
// sequential __builtin_fmaf chain over its taps in row-major (i,j) order,
// fp32 accumulator starting at 0, weights fp32(1/15), fp32(1/9); replicate
// boundary; 8 iterations; fp32 iterates; fp32 d/argmin(first-idx)/update;
// final clip(|x0-res|,0,255).
//
// R22 = R19's pair body (best: 57 us/dispatch, VGPR 84) with the grid
// CONDENSED 8x: each block walks 8 consecutive y-pairs in a rolled loop.
//  - 768 blocks = 3 blocks/CU = exactly the (3,3) residency cap -> full
//    occupancy from t=0, ONE generation (R19 had 24 sequential block
//    generations per CU, each restarting with cold L1).
//  - Consecutive y-pairs share 4 of 6 window rows; the block's 24 KB
//    row-strip working set fits the 32 KB L1, so those loads become
//    L1 hits (~40 cyc) instead of L2/HBM (200-900 cyc). This attacks
//    the measured 26 us of un-overlapped latency (VALU 31 + L1 19 +
//    HBM 20 us pipes vs 57 us wall).
//  - XCD banding inherited: each block stays inside one XCD's
//    contiguous 128-pair band (R17/R19-proven FETCH win).
// Per-ypair math/loads byte-identical to R19 (bit-exact, 15 float4
// loads per 8 outputs). Edge path = inline halo-clamped scalar loads
// (proven absmax 0.0 in R16/R18/R20), liveness-local to the branch.

static constexpr int H      = 2048;
static constexpr int W      = 2048;
static constexpr int C      = 3;
static constexpr int WC     = W * C;       // 6144 floats per row
static constexpr int NBX    = 6;           // x-blocks (256 thr x 4 cols)
static constexpr int NPAIRS = H / 2;       // 1024 row-pairs
static constexpr int PY     = 8;           // y-pairs walked per block
static constexpr int NYG    = NPAIRS / PY; // 128 y-groups
static constexpr int NBLK   = NBX * NYG;   // 768 blocks
static constexpr int YGX    = NYG / 8;     // 16 y-groups per XCD

// One window-row phase of the 8 directional chains for one output column.
// ph is compile-time at every call site (unrolled loops) so branches fold.
// Chain statement order is IDENTICAL to the verified R10/R15/R19 kernels.
__device__ __forceinline__ void apply_phase_t(float* __restrict__ a,
                                              float t0, float t1, float t2,
                                              float t3, float t4,
                                              int ph, float& center,
                                              float w15, float w9) {
  if (ph == 2) center = t2;
  // L: cols 0..2, all rows
  a[0]=__builtin_fmaf(w15,t0,a[0]); a[0]=__builtin_fmaf(w15,t1,a[0]); a[0]=__builtin_fmaf(w15,t2,a[0]);
  // R: cols 2..4, all rows
  a[1]=__builtin_fmaf(w15,t2,a[1]); a[1]=__builtin_fmaf(w15,t3,a[1]); a[1]=__builtin_fmaf(w15,t4,a[1]);
  if (ph <= 2) {  // U: rows 0..2, all cols
    a[2]=__builtin_fmaf(w15,t0,a[2]); a[2]=__builtin_fmaf(w15,t1,a[2]); a[2]=__builtin_fmaf(w15,t2,a[2]);
    a[2]=__builtin_fmaf(w15,t3,a[2]); a[2]=__builtin_fmaf(w15,t4,a[2]);
    // NW / NE
    a[4]=__builtin_fmaf(w9,t0,a[4]); a[4]=__builtin_fmaf(w9,t1,a[4]); a[4]=__builtin_fmaf(w9,t2,a[4]);
    a[5]=__builtin_fmaf(w9,t2,a[5]); a[5]=__builtin_fmaf(w9,t3,a[5]); a[5]=__builtin_fmaf(w9,t4,a[5]);
  }
  if (ph >= 2) {  // D: rows 2..4, all cols
    a[3]=__builtin_fmaf(w15,t0,a[3]); a[3]=__builtin_fmaf(w15,t1,a[3]); a[3]=__builtin_fmaf(w15,t2,a[3]);
    a[3]=__builtin_fmaf(w15,t3,a[3]); a[3]=__builtin_fmaf(w15,t4,a[3]);
    // SW / SE
    a[6]=__builtin_fmaf(w9,t0,a[6]); a[6]=__builtin_fmaf(w9,t1,a[6]); a[6]=__builtin_fmaf(w9,t2,a[6]);
    a[7]=__builtin_fmaf(w9,t2,a[7]); a[7]=__builtin_fmaf(w9,t3,a[7]); a[7]=__builtin_fmaf(w9,t4,a[7]);
  }
}

// fp32 d/argmin/update epilogue for one output column (order-contractual).
__device__ __forceinline__ float finish(const float* __restrict__ a,
                                        float center) {
  float best  = a[0] - center;
  float besta = fabsf(best);
#pragma unroll
  for (int m = 1; m < 8; ++m) {
    const float d  = a[m] - center;
    const float ab = fabsf(d);
    if (ab < besta) { besta = ab; best = d; }
  }
  return center + best;
}

template<bool FINAL>
__global__ __attribute__((amdgpu_waves_per_eu(3, 3))) __launch_bounds__(256)
void swf_gc(const float* __restrict__ src, float* __restrict__ dst,
            const float* __restrict__ x0) {
  // block -> (xcd band, y-group, x-strip); block walks PY y-pairs
  const int gid    = blockIdx.x;            // 0..767
  const int xcd    = gid & 7;
  const int sub    = gid >> 3;              // 0..95
  const int yg     = sub / NBX;             // 0..15
  const int xb     = sub - yg * NBX;        // 0..5
  const int ypair0 = xcd * (YGX * PY) + yg * PY;   // contiguous in-band
  const int col4   = (xb * 256 + threadIdx.x) * 4; // 16B-aligned

  const float w15 = 1.0f / 15.0f;   // fp32(1/15)
  const float w9  = 1.0f / 9.0f;    // fp32(1/9)

  // fast iff all taps for cols col4..col4+3 lie in [col4-8, col4+12)
  const bool fastc = (col4 >= 8) && (col4 <= WC - 12);

#pragma unroll 1
  for (int p = 0; p < PY; ++p) {
    const int yA = (ypair0 + p) * 2;        // rows yA, yA+1

    float accA[4][8], accB[4][8];
#pragma unroll
    for (int k = 0; k < 4; ++k)
#pragma unroll
      for (int m = 0; m < 8; ++m) { accA[k][m] = 0.0f; accB[k][m] = 0.0f; }
    float centerA[4], centerB[4];

    if (fastc) {
      const float* colbase = src + (col4 - 8);
      // walk the 6-row union: row yA+i-2 feeds phase i of A (i<=4) and
      // phase i-1 of B (i>=1)
#pragma unroll
      for (int i = 0; i < 6; ++i) {
        int hy = yA + i - 2;
        hy = hy < 0 ? 0 : (hy > H - 1 ? H - 1 : hy);   // replicate rows
        const float4* rp = (const float4*)(colbase + (size_t)hy * WC);
        const float4 q0 = rp[0], q1 = rp[1], q2 = rp[2], q3 = rp[3], q4 = rp[4];
        const float r[20] = {q0.x,q0.y,q0.z,q0.w, q1.x,q1.y,q1.z,q1.w,
                             q2.x,q2.y,q2.z,q2.w, q3.x,q3.y,q3.z,q3.w,
                             q4.x,q4.y,q4.z,q4.w};
#pragma unroll
        for (int k = 0; k < 4; ++k) {
          // tap j of output col4+k -> r[k + 3j + 2]
          const float t0 = r[k+2], t1 = r[k+5], t2 = r[k+8],
                      t3 = r[k+11], t4 = r[k+14];
          if (i <= 4) apply_phase_t(accA[k], t0,t1,t2,t3,t4, i,     centerA[k], w15, w9);
          if (i >= 1) apply_phase_t(accB[k], t0,t1,t2,t3,t4, i - 1, centerB[k], w15, w9);
        }
      }
    } else {
      // edge columns (col4 in {0,4,WC-8,WC-4}): build the same 20-float
      // window per row via pixel-clamped scalar loads (halo identity,
      // verified absmax 0.0 in R16/R18/R20: float x <-> unclamped idx
      // f = col4-8+x; f<0 -> ((f%3)+3)%3, f>=WC -> (W-1)*3+f%3).
      const int base = col4 - 8;
#pragma unroll
      for (int i = 0; i < 6; ++i) {
        int hy = yA + i - 2;
        hy = hy < 0 ? 0 : (hy > H - 1 ? H - 1 : hy);
        const float* rr = src + (size_t)hy * WC;
        float r[20];
#pragma unroll
        for (int x = 0; x < 20; ++x) {
          const int f  = base + x;
          const int ix = (f < 0)    ? ((f % 3) + 3) % 3
                       : (f >= WC)  ? (W - 1) * 3 + (f % 3)
                       : f;
          r[x] = rr[ix];
        }
#pragma unroll
        for (int k = 0; k < 4; ++k) {
          const float t0 = r[k+2], t1 = r[k+5], t2 = r[k+8],
                      t3 = r[k+11], t4 = r[k+14];
          if (i <= 4) apply_phase_t(accA[k], t0,t1,t2,t3,t4, i,     centerA[k], w15, w9);
          if (i >= 1) apply_phase_t(accB[k], t0,t1,t2,t3,t4, i - 1, centerB[k], w15, w9);
        }
      }
    }

    // epilogue: two output rows, fp32 d/argmin/update, float4 stores
#pragma unroll
    for (int half = 0; half < 2; ++half) {
      const int y = yA + half;
      float4 xv4;
      if (FINAL) xv4 = *(const float4*)(x0 + (size_t)y * WC + col4);
      float o[4];
#pragma unroll
      for (int k = 0; k < 4; ++k) {
        const float res = half ? finish(accB[k], centerB[k])
                               : finish(accA[k], centerA[k]);
        if (FINAL) {
          const float xv = (k == 0) ? xv4.x : (k == 1) ? xv4.y
                         : (k == 2) ? xv4.z : xv4.w;
          float diff = fabsf(xv - res);
          o[k] = diff > 255.0f ? 255.0f : diff;
        } else {
          o[k] = res;
        }
      }
      float4 ov;
      ov.x = o[0]; ov.y = o[1]; ov.z = o[2]; ov.w = o[3];
      *(float4*)(dst + (size_t)y * WC + col4) = ov;
    }
  }
}

extern "C" void kernel_launch(void* const* d_in, const int* in_sizes, int n_in,
                              void* d_out, int out_size, void* d_ws, size_t ws_size,
                              hipStream_t stream) {
  const float* x0  = (const float*)d_in[0];
  float*       out = (float*)d_out;
  float*       ws  = (float*)d_ws;   // needs H*W*C*4 = 50.3 MB

  dim3 grid(NBLK);                   // 768 blocks = 3/CU, full residency
  dim3 block(256);

  swf_gc<false><<<grid, block, 0, stream>>>(x0,  ws,  nullptr);  // iter 1
  swf_gc<false><<<grid, block, 0, stream>>>(ws,  out, nullptr);  // iter 2
  swf_gc<false><<<grid, block, 0, stream>>>(out, ws,  nullptr);  // iter 3
  swf_gc<false><<<grid, block, 0, stream>>>(ws,  out, nullptr);  // iter 4
  swf_gc<false><<<grid, block, 0, stream>>>(out, ws,  nullptr);  // iter 5
  swf_gc<false><<<grid, block, 0, stream>>>(ws,  out, nullptr);  // iter 6
  swf_gc<false><<<grid, block, 0, stream>>>(out, ws,  nullptr);  // iter 7
  swf_gc<true ><<<grid, block, 0, stream>>>(ws,  out, x0);       // iter 8 + diff
}